// Round 1
// baseline (155.430 us; speedup 1.0000x reference)
//
#include <hip/hip_runtime.h>

#define T_DIM 16384
#define EPS 1e-7f

__global__ __launch_bounds__(256) void reinforce_reduce(
    const float* __restrict__ log_probs,
    const float* __restrict__ logits,
    const float* __restrict__ weight,
    double* __restrict__ ws,
    long long n4)  // number of float4 elements
{
    double num = 0.0, den = 0.0;
    const long long stride = (long long)gridDim.x * blockDim.x;
    for (long long i = (long long)blockIdx.x * blockDim.x + threadIdx.x;
         i < n4; i += stride) {
        const float4 lp = ((const float4*)log_probs)[i];
        const float4 z  = ((const float4*)logits)[i];
        const float4 w  = ((const float4*)weight)[i];
        const long long base = i << 2;
        const int s = (int)(base & (long long)(T_DIM - 1));  // column index

        // rewards = log(sigmoid(z)+eps); term = w*w*r*lp; weighted by (s+1)
        float sig0 = 1.0f / (1.0f + __expf(-z.x));
        float sig1 = 1.0f / (1.0f + __expf(-z.y));
        float sig2 = 1.0f / (1.0f + __expf(-z.z));
        float sig3 = 1.0f / (1.0f + __expf(-z.w));
        float r0 = __logf(sig0 + EPS);
        float r1 = __logf(sig1 + EPS);
        float r2 = __logf(sig2 + EPS);
        float r3 = __logf(sig3 + EPS);
        float t0 = w.x * w.x * r0 * lp.x;
        float t1 = w.y * w.y * r1 * lp.y;
        float t2 = w.z * w.z * r2 * lp.z;
        float t3 = w.w * w.w * r3 * lp.w;

        num += (double)t0 * (double)(s + 1)
             + (double)t1 * (double)(s + 2)
             + (double)t2 * (double)(s + 3)
             + (double)t3 * (double)(s + 4);
        den += (double)w.x + (double)w.y + (double)w.z + (double)w.w;
    }

    // wave-level butterfly reduce (64 lanes)
    #pragma unroll
    for (int off = 32; off > 0; off >>= 1) {
        num += __shfl_down(num, off, 64);
        den += __shfl_down(den, off, 64);
    }

    __shared__ double s_num[4], s_den[4];
    const int lane = threadIdx.x & 63;
    const int wid  = threadIdx.x >> 6;
    if (lane == 0) { s_num[wid] = num; s_den[wid] = den; }
    __syncthreads();
    if (threadIdx.x == 0) {
        double n = s_num[0] + s_num[1] + s_num[2] + s_num[3];
        double d = s_den[0] + s_den[1] + s_den[2] + s_den[3];
        atomicAdd(&ws[0], n);
        atomicAdd(&ws[1], d);
    }
}

__global__ void reinforce_finalize(const double* __restrict__ ws,
                                   float* __restrict__ out)
{
    out[0] = (float)(ws[0] / ws[1]);
}

extern "C" void kernel_launch(void* const* d_in, const int* in_sizes, int n_in,
                              void* d_out, int out_size, void* d_ws, size_t ws_size,
                              hipStream_t stream) {
    const float* log_probs = (const float*)d_in[0];
    const float* logits    = (const float*)d_in[1];
    const float* weight    = (const float*)d_in[2];
    float* out = (float*)d_out;
    double* ws = (double*)d_ws;

    const long long N  = (long long)in_sizes[0];  // B*T
    const long long n4 = N >> 2;

    // ws is re-poisoned to 0xAA before every launch — zero the accumulators.
    hipMemsetAsync(ws, 0, 2 * sizeof(double), stream);

    const int block = 256;
    const int grid  = 2048;  // 8 wg/CU over 256 CUs; grid-stride covers n4
    reinforce_reduce<<<grid, block, 0, stream>>>(log_probs, logits, weight, ws, n4);
    reinforce_finalize<<<1, 1, 0, stream>>>(ws, out);
}